// Round 12
// baseline (137.293 us; speedup 1.0000x reference)
//
#include <hip/hip_runtime.h>
#include <math.h>

#define NA 8192
#define NE 32768
#define NT 256
#define JSPLIT 32
#define JCHUNK (NA / JSPLIT)   /* 256 j-atoms per steric tile */
#define NIB 16                 /* i-blocks: NA/(NT*2), ITILE=2 */

// ---- workspace layout (4-byte element offsets) ----
#define WS_DEG      0                      // int NA
#define WS_LOSS     (WS_DEG + NA)          // f32 4  [0]=valence [1]=bond [2]=steric
#define WS_DD       (WS_LOSS + 4)          // f32 3NA  combined push+bond delta
#define WS_ZERO_END (WS_DD + 3*NA)         // memset zeroes [0, here) = 131 KB
#define WS_PART     ((WS_ZERO_END + 3) & ~3)  // float4 JSPLIT*NA = 4 MB, 16B aligned

// ---- chemistry tables (types present: {1,6,7,8,9,15,16,17}) ----
__device__ __forceinline__ float maxval_of(int z) {
    switch (z) {
        case 1: return 1.f; case 6: return 4.f; case 7: return 3.f; case 8: return 2.f;
        case 9: return 1.f; case 15: return 5.f; case 16: return 6.f; case 17: return 1.f;
        case 35: return 1.f; case 53: return 1.f; default: return 4.f;
    }
}
__device__ __forceinline__ float vdw_of(int z) {
    switch (z) {
        case 1: return 1.2f; case 6: return 1.7f; case 7: return 1.55f; case 8: return 1.52f;
        case 9: return 1.47f; case 15: return 1.8f; case 16: return 1.8f; case 17: return 1.75f;
        case 35: return 1.85f; case 53: return 1.98f; default: return 1.6f;
    }
}
__device__ __forceinline__ float bond_of(int a, int b) {
    int lo = a < b ? a : b, hi = a < b ? b : a;
    switch (lo * 64 + hi) {
        case 6*64+6:   return 1.54f;
        case 6*64+7:   return 1.47f;
        case 6*64+8:   return 1.43f;
        case 6*64+16:  return 1.82f;
        case 6*64+9:   return 1.35f;
        case 6*64+17:  return 1.77f;
        case 1*64+6:   return 1.09f;
        case 7*64+7:   return 1.45f;
        case 7*64+8:   return 1.40f;
        case 1*64+7:   return 1.01f;
        case 8*64+8:   return 1.48f;
        case 1*64+8:   return 0.96f;
        case 16*64+16: return 2.05f;
        case 8*64+15:  return 1.63f;
        default:       return 1.5f;
    }
}
__device__ __forceinline__ float viol_of(int d, int z) {
    return fmaxf((float)d - maxval_of(z), 0.f);
}

__device__ __forceinline__ float wave_reduce_sum(float x) {
    #pragma unroll
    for (int off = 32; off > 0; off >>= 1) x += __shfl_down(x, off);
    return x;  // valid in lane 0 of each wave
}

// ---- 1. out-degree histogram (int atomics only; must precede k_edge) ----
__global__ void k_deg(const int* __restrict__ row, int* __restrict__ deg) {
    int e = blockIdx.x * NT + threadIdx.x;
    if (e < NE) atomicAdd(&deg[row[e]], 1);
}

// ---- 2. fused bond + valence push + both losses (round-10 form, kept: -6 us) ----
__global__ void k_edge(const int* __restrict__ row, const int* __restrict__ col,
                       const int* __restrict__ types, const int* __restrict__ deg,
                       const float* __restrict__ pos, float* __restrict__ dD,
                       float* __restrict__ lossAcc) {
    int e = blockIdx.x * NT + threadIdx.x;
    float l1 = 0.f, l0 = 0.f;
    if (e < NE) {
        int r = row[e], c = col[e];
        float bx = pos[3*r]   - pos[3*c];
        float by = pos[3*r+1] - pos[3*c+1];
        float bz = pos[3*r+2] - pos[3*c+2];
        float cur = sqrtf(bx*bx + by*by + bz*bz);
        float tgt = bond_of(types[r], types[c]);
        float diff = cur - tgt;
        l1 = diff * diff;
        float rcur = 1.0f / (cur + 1e-8f);        // single divide
        float ratio = fminf(fmaxf(tgt * rcur, 0.98f), 1.02f);
        float s = (ratio - 1.f) * 0.005f;
        float v = viol_of(deg[r], types[r]);
        float sc = (v > 0.f) ? (v * 1e-3f * rcur) : 0.f;   // self-edge: b=0 anyway
        float rs = s + sc;
        atomicAdd(&dD[3*r],   bx * rs);
        atomicAdd(&dD[3*r+1], by * rs);
        atomicAdd(&dD[3*r+2], bz * rs);
        atomicAdd(&dD[3*c],   -bx * s);
        atomicAdd(&dD[3*c+1], -by * s);
        atomicAdd(&dD[3*c+2], -bz * s);
    }
    if (e < NA) {                              // valence loss (deg complete here)
        float v = viol_of(deg[e], types[e]);
        l0 = v * v;
    }
    float p1 = wave_reduce_sum(l1);
    float p0 = wave_reduce_sum(l0);
    if ((threadIdx.x & 63) == 0) {
        if (p1 != 0.f) atomicAdd(&lossAcc[1], p1);
        if (p0 != 0.f) atomicAdd(&lossAcc[0], p0);
    }
}

// round-9 tail (proven fastest arithmetic form), predicated by precomputed hit flag
__device__ __forceinline__ void steric_tail(float d2, float md, bool hit, const float4 q,
                                            float& cs, float& sx, float& sy, float& sz,
                                            float& ll) {
    float rinv = rsqrtf(fmaxf(d2, 1e-12f));
    float dist = d2 * rinv;
    float t1 = md - dist;
    float t1c = hit ? t1 : 0.f;
    ll = fmaf(t1c, t1c, ll);
    float co = t1c * rinv;
    cs += co;
    sx = fmaf(co, q.x, sx);
    sy = fmaf(co, q.y, sy);
    sz = fmaf(co, q.z, sz);
}

// ---- 3. steric all-pairs -> non-atomic partial[y][a] (512 blocks, ITILE=2,
//      JCHUNK=256) with wave-uniform early-out: hit iff d2 < md^2 (no rsqrt
//      needed for the test); ~37% of wave-iterations have zero hits across all
//      128 lane-pairs and skip the rsqrt tail entirely. ----
__global__ void __launch_bounds__(NT)
k_steric(const float* __restrict__ pos, const float* __restrict__ dD,
         const int* __restrict__ types, float4* __restrict__ partial,
         float* __restrict__ lossAcc) {
    __shared__ float4 sm[JCHUNK];
    const int t = threadIdx.x;
    const int b = blockIdx.x;
    const int yb = b >> 4;                 // [0,32) j-slice
    const int ib = b & 15;                 // [0,16) i-block of 512 atoms
    int j = yb * JCHUNK + t;
    sm[t] = make_float4(pos[3*j]   + dD[3*j],
                        pos[3*j+1] + dD[3*j+1],
                        pos[3*j+2] + dD[3*j+2],
                        vdw_of(types[j]) * 0.8f);
    const int i0 = ib * 512 + t;
    const int i1 = i0 + 256;
    float4 p0 = make_float4(pos[3*i0] + dD[3*i0], pos[3*i0+1] + dD[3*i0+1],
                            pos[3*i0+2] + dD[3*i0+2], vdw_of(types[i0]) * 0.8f);
    float4 p1 = make_float4(pos[3*i1] + dD[3*i1], pos[3*i1+1] + dD[3*i1+1],
                            pos[3*i1+2] + dD[3*i1+2], vdw_of(types[i1]) * 0.8f);
    __syncthreads();
    float cs0 = 0.f, sx0 = 0.f, sy0 = 0.f, sz0 = 0.f;
    float cs1 = 0.f, sx1 = 0.f, sy1 = 0.f, sz1 = 0.f;
    float ll = 0.f;
    #pragma unroll 4
    for (int jj = 0; jj < JCHUNK; jj++) {
        float4 q = sm[jj];
        // always-path: squared distances + hit tests (no transcendentals)
        float dx0 = p0.x - q.x, dy0 = p0.y - q.y, dz0 = p0.z - q.z;
        float d20 = fmaf(dx0, dx0, fmaf(dy0, dy0, dz0 * dz0));
        float md0 = p0.w + q.w;
        float dx1 = p1.x - q.x, dy1 = p1.y - q.y, dz1 = p1.z - q.z;
        float d21 = fmaf(dx1, dx1, fmaf(dy1, dy1, dz1 * dz1));
        float md1 = p1.w + q.w;
        // d2 > 1e-12 excludes exactly the diagonal (min real pair dist ~0.04)
        bool h0 = (d20 < md0 * md0) && (d20 > 1e-12f);
        bool h1 = (d21 < md1 * md1) && (d21 > 1e-12f);
        if (__any(h0 | h1)) {
            steric_tail(d20, md0, h0, q, cs0, sx0, sy0, sz0, ll);
            steric_tail(d21, md1, h1, q, cs1, sx1, sy1, sz1, ll);
        }
    }
    partial[yb * NA + i0] = make_float4(cs0, sx0, sy0, sz0);
    partial[yb * NA + i1] = make_float4(cs1, sx1, sy1, sz1);
    float part = wave_reduce_sum(ll);
    if ((t & 63) == 0 && part != 0.f) atomicAdd(&lossAcc[2], part);
}

// ---- 4. reduce 32 slices/atom (coalesced) + final output + loss scalar ----
__global__ void k_reduce(const float* __restrict__ pos, const float* __restrict__ dD,
                         const float4* __restrict__ partial,
                         const float* __restrict__ lossAcc, float* __restrict__ out) {
    int a = blockIdx.x * NT + threadIdx.x;   // 32 blocks x 256 = NA
    float cs = 0.f, sx = 0.f, sy = 0.f, sz = 0.f;
    #pragma unroll 8
    for (int y = 0; y < JSPLIT; y++) {
        float4 u = partial[y * NA + a];      // coalesced: consecutive a per lane
        cs += u.x; sx += u.y; sy += u.z; sz += u.w;
    }
    float px = pos[3*a]   + dD[3*a];
    float py = pos[3*a+1] + dD[3*a+1];
    float pz = pos[3*a+2] + dD[3*a+2];
    float c = 1.f + cs * 0.0025f;
    out[3*a]   = px * c - sx * 0.0025f;
    out[3*a+1] = py * c - sy * 0.0025f;
    out[3*a+2] = pz * c - sz * 0.0025f;
    if (a == 0) {
        float loss = lossAcc[0] + lossAcc[1] * (1.f / NE) + lossAcc[2] * 0.5f;
        out[3*NA] = loss * 0.1f;
    }
}

extern "C" void kernel_launch(void* const* d_in, const int* in_sizes, int n_in,
                              void* d_out, int out_size, void* d_ws, size_t ws_size,
                              hipStream_t stream) {
    (void)in_sizes; (void)n_in; (void)out_size; (void)ws_size;
    const float* pos   = (const float*)d_in[0];
    const int*   eidx  = (const int*)d_in[1];
    const int*   types = (const int*)d_in[2];
    const int* row = eidx;
    const int* col = eidx + NE;

    int*   ws_i = (int*)d_ws;
    float* ws_f = (float*)d_ws;
    int*    deg     = ws_i + WS_DEG;
    float*  lossAcc = ws_f + WS_LOSS;
    float*  dD      = ws_f + WS_DD;
    float4* partial = (float4*)(ws_f + WS_PART);
    float*  out     = (float*)d_out;

    hipMemsetAsync(d_ws, 0, (size_t)WS_ZERO_END * 4, stream);  // deg, loss, dD
    k_deg   <<<NE/NT, NT, 0, stream>>>(row, deg);
    k_edge  <<<NE/NT, NT, 0, stream>>>(row, col, types, deg, pos, dD, lossAcc);
    k_steric<<<JSPLIT*NIB, NT, 0, stream>>>(pos, dD, types, partial, lossAcc);
    k_reduce<<<NA/NT, NT, 0, stream>>>(pos, dD, partial, lossAcc, out);
}

// Round 13
// 133.176 us; speedup vs baseline: 1.0309x; 1.0309x over previous
//
#include <hip/hip_runtime.h>
#include <math.h>

#define NA 8192
#define NE 32768
#define NT 256
#define JSPLIT 32
#define JCHUNK (NA / JSPLIT)   /* 256 j-atoms per steric tile */
#define NIB 16                 /* i-blocks: NA/(NT*2), ITILE=2 */

// ---- workspace layout (4-byte element offsets) ----
#define WS_DEG      0                      // int NA
#define WS_LOSS     (WS_DEG + NA)          // f32 4  [0]=valence [1]=bond [2]=steric
#define WS_DD       (WS_LOSS + 4)          // f32 3NA  combined push+bond delta
#define WS_ZERO_END (WS_DD + 3*NA)         // memset zeroes [0, here) = 131 KB
#define WS_PART     ((WS_ZERO_END + 3) & ~3)  // float4 JSPLIT*NA = 4 MB, 16B aligned

// ---- chemistry tables (types present: {1,6,7,8,9,15,16,17}) ----
__device__ __forceinline__ float maxval_of(int z) {
    switch (z) {
        case 1: return 1.f; case 6: return 4.f; case 7: return 3.f; case 8: return 2.f;
        case 9: return 1.f; case 15: return 5.f; case 16: return 6.f; case 17: return 1.f;
        case 35: return 1.f; case 53: return 1.f; default: return 4.f;
    }
}
__device__ __forceinline__ float vdw_of(int z) {
    switch (z) {
        case 1: return 1.2f; case 6: return 1.7f; case 7: return 1.55f; case 8: return 1.52f;
        case 9: return 1.47f; case 15: return 1.8f; case 16: return 1.8f; case 17: return 1.75f;
        case 35: return 1.85f; case 53: return 1.98f; default: return 1.6f;
    }
}
__device__ __forceinline__ float bond_of(int a, int b) {
    int lo = a < b ? a : b, hi = a < b ? b : a;
    switch (lo * 64 + hi) {
        case 6*64+6:   return 1.54f;
        case 6*64+7:   return 1.47f;
        case 6*64+8:   return 1.43f;
        case 6*64+16:  return 1.82f;
        case 6*64+9:   return 1.35f;
        case 6*64+17:  return 1.77f;
        case 1*64+6:   return 1.09f;
        case 7*64+7:   return 1.45f;
        case 7*64+8:   return 1.40f;
        case 1*64+7:   return 1.01f;
        case 8*64+8:   return 1.48f;
        case 1*64+8:   return 0.96f;
        case 16*64+16: return 2.05f;
        case 8*64+15:  return 1.63f;
        default:       return 1.5f;
    }
}
__device__ __forceinline__ float viol_of(int d, int z) {
    return fmaxf((float)d - maxval_of(z), 0.f);
}

__device__ __forceinline__ float wave_reduce_sum(float x) {
    #pragma unroll
    for (int off = 32; off > 0; off >>= 1) x += __shfl_down(x, off);
    return x;  // valid in lane 0 of each wave
}

// ---- packed-f32 helpers: element-wise float2 ops the SLP vectorizer can fuse
//      into VOP3P v_pk_{fma,add,mul}_f32 (full-rate dual FP32 on CDNA) ----
__device__ __forceinline__ float2 pk(float a, float b) { return make_float2(a, b); }
__device__ __forceinline__ float2 pk_fma(float2 a, float2 b, float2 c) {
    return make_float2(fmaf(a.x, b.x, c.x), fmaf(a.y, b.y, c.y));
}
__device__ __forceinline__ float2 pk_add(float2 a, float2 b) {
    return make_float2(a.x + b.x, a.y + b.y);
}
__device__ __forceinline__ float2 pk_sub(float2 a, float2 b) {
    return make_float2(a.x - b.x, a.y - b.y);
}
__device__ __forceinline__ float2 pk_mul(float2 a, float2 b) {
    return make_float2(a.x * b.x, a.y * b.y);
}

// ---- 1. out-degree histogram (int atomics only; must precede k_edge) ----
__global__ void k_deg(const int* __restrict__ row, int* __restrict__ deg) {
    int e = blockIdx.x * NT + threadIdx.x;
    if (e < NE) atomicAdd(&deg[row[e]], 1);
}

// ---- 2. fused bond + valence push + both losses (round-10 form, kept: -6 us) ----
__global__ void k_edge(const int* __restrict__ row, const int* __restrict__ col,
                       const int* __restrict__ types, const int* __restrict__ deg,
                       const float* __restrict__ pos, float* __restrict__ dD,
                       float* __restrict__ lossAcc) {
    int e = blockIdx.x * NT + threadIdx.x;
    float l1 = 0.f, l0 = 0.f;
    if (e < NE) {
        int r = row[e], c = col[e];
        float bx = pos[3*r]   - pos[3*c];
        float by = pos[3*r+1] - pos[3*c+1];
        float bz = pos[3*r+2] - pos[3*c+2];
        float cur = sqrtf(bx*bx + by*by + bz*bz);
        float tgt = bond_of(types[r], types[c]);
        float diff = cur - tgt;
        l1 = diff * diff;
        float rcur = 1.0f / (cur + 1e-8f);        // single divide
        float ratio = fminf(fmaxf(tgt * rcur, 0.98f), 1.02f);
        float s = (ratio - 1.f) * 0.005f;
        float v = viol_of(deg[r], types[r]);
        float sc = (v > 0.f) ? (v * 1e-3f * rcur) : 0.f;   // self-edge: b=0 anyway
        float rs = s + sc;
        atomicAdd(&dD[3*r],   bx * rs);
        atomicAdd(&dD[3*r+1], by * rs);
        atomicAdd(&dD[3*r+2], bz * rs);
        atomicAdd(&dD[3*c],   -bx * s);
        atomicAdd(&dD[3*c+1], -by * s);
        atomicAdd(&dD[3*c+2], -bz * s);
    }
    if (e < NA) {                              // valence loss (deg complete here)
        float v = viol_of(deg[e], types[e]);
        l0 = v * v;
    }
    float p1 = wave_reduce_sum(l1);
    float p0 = wave_reduce_sum(l0);
    if ((threadIdx.x & 63) == 0) {
        if (p1 != 0.f) atomicAdd(&lossAcc[1], p1);
        if (p0 != 0.f) atomicAdd(&lossAcc[0], p0);
    }
}

// ---- 3. steric all-pairs -> non-atomic partial[y][a] (512 blocks, ITILE=2,
//      JCHUNK=256). Round-9 arithmetic per half, SoA-packed across the two
//      i-atoms so main-path FMAs fuse into v_pk_*_f32. Straight-line loop,
//      no branches (R12 proved branches cost more than the skipped work). ----
__global__ void __launch_bounds__(NT)
k_steric(const float* __restrict__ pos, const float* __restrict__ dD,
         const int* __restrict__ types, float4* __restrict__ partial,
         float* __restrict__ lossAcc) {
    __shared__ float4 sm[JCHUNK];
    const int t = threadIdx.x;
    const int b = blockIdx.x;
    const int yb = b >> 4;                 // [0,32) j-slice
    const int ib = b & 15;                 // [0,16) i-block of 512 atoms
    int j = yb * JCHUNK + t;
    sm[t] = make_float4(pos[3*j]   + dD[3*j],
                        pos[3*j+1] + dD[3*j+1],
                        pos[3*j+2] + dD[3*j+2],
                        vdw_of(types[j]) * 0.8f);
    const int i0 = ib * 512 + t;
    const int i1 = i0 + 256;
    // SoA across the two i-atoms: {i0, i1} per component
    float2 pix = pk(pos[3*i0]   + dD[3*i0],   pos[3*i1]   + dD[3*i1]);
    float2 piy = pk(pos[3*i0+1] + dD[3*i0+1], pos[3*i1+1] + dD[3*i1+1]);
    float2 piz = pk(pos[3*i0+2] + dD[3*i0+2], pos[3*i1+2] + dD[3*i1+2]);
    float2 piw = pk(vdw_of(types[i0]) * 0.8f, vdw_of(types[i1]) * 0.8f);
    __syncthreads();
    float2 cs2 = pk(0.f, 0.f), sx2 = pk(0.f, 0.f), sy2 = pk(0.f, 0.f),
           sz2 = pk(0.f, 0.f), ll2 = pk(0.f, 0.f);
    #pragma unroll 8
    for (int jj = 0; jj < JCHUNK; jj++) {
        float4 q = sm[jj];
        float2 qx = pk(q.x, q.x), qy = pk(q.y, q.y), qz = pk(q.z, q.z),
               qw = pk(q.w, q.w);
        float2 dx = pk_sub(pix, qx);
        float2 dy = pk_sub(piy, qy);
        float2 dz = pk_sub(piz, qz);
        float2 d2 = pk_fma(dx, dx, pk_fma(dy, dy, pk_mul(dz, dz)));
        float2 md = pk_add(piw, qw);
        // rsqrt: transcendental, scalar per half (round-9 exact form)
        float2 rinv = pk(rsqrtf(fmaxf(d2.x, 1e-12f)),
                         rsqrtf(fmaxf(d2.y, 1e-12f)));
        float2 dist = pk_mul(d2, rinv);
        float2 t1 = pk_sub(md, dist);
        // d2 > 1e-12 excludes exactly the diagonal (min real pair dist ~0.04)
        float t1c0 = (t1.x > 0.f && d2.x > 1e-12f) ? t1.x : 0.f;
        float t1c1 = (t1.y > 0.f && d2.y > 1e-12f) ? t1.y : 0.f;
        float2 t1c = pk(t1c0, t1c1);
        ll2 = pk_fma(t1c, t1c, ll2);
        float2 co = pk_mul(t1c, rinv);
        cs2 = pk_add(cs2, co);
        sx2 = pk_fma(co, qx, sx2);
        sy2 = pk_fma(co, qy, sy2);
        sz2 = pk_fma(co, qz, sz2);
    }
    partial[yb * NA + i0] = make_float4(cs2.x, sx2.x, sy2.x, sz2.x);
    partial[yb * NA + i1] = make_float4(cs2.y, sx2.y, sy2.y, sz2.y);
    float part = wave_reduce_sum(ll2.x + ll2.y);
    if ((t & 63) == 0 && part != 0.f) atomicAdd(&lossAcc[2], part);
}

// ---- 4. reduce 32 slices/atom (coalesced) + final output + loss scalar ----
__global__ void k_reduce(const float* __restrict__ pos, const float* __restrict__ dD,
                         const float4* __restrict__ partial,
                         const float* __restrict__ lossAcc, float* __restrict__ out) {
    int a = blockIdx.x * NT + threadIdx.x;   // 32 blocks x 256 = NA
    float cs = 0.f, sx = 0.f, sy = 0.f, sz = 0.f;
    #pragma unroll 8
    for (int y = 0; y < JSPLIT; y++) {
        float4 u = partial[y * NA + a];      // coalesced: consecutive a per lane
        cs += u.x; sx += u.y; sy += u.z; sz += u.w;
    }
    float px = pos[3*a]   + dD[3*a];
    float py = pos[3*a+1] + dD[3*a+1];
    float pz = pos[3*a+2] + dD[3*a+2];
    float c = 1.f + cs * 0.0025f;
    out[3*a]   = px * c - sx * 0.0025f;
    out[3*a+1] = py * c - sy * 0.0025f;
    out[3*a+2] = pz * c - sz * 0.0025f;
    if (a == 0) {
        float loss = lossAcc[0] + lossAcc[1] * (1.f / NE) + lossAcc[2] * 0.5f;
        out[3*NA] = loss * 0.1f;
    }
}

extern "C" void kernel_launch(void* const* d_in, const int* in_sizes, int n_in,
                              void* d_out, int out_size, void* d_ws, size_t ws_size,
                              hipStream_t stream) {
    (void)in_sizes; (void)n_in; (void)out_size; (void)ws_size;
    const float* pos   = (const float*)d_in[0];
    const int*   eidx  = (const int*)d_in[1];
    const int*   types = (const int*)d_in[2];
    const int* row = eidx;
    const int* col = eidx + NE;

    int*   ws_i = (int*)d_ws;
    float* ws_f = (float*)d_ws;
    int*    deg     = ws_i + WS_DEG;
    float*  lossAcc = ws_f + WS_LOSS;
    float*  dD      = ws_f + WS_DD;
    float4* partial = (float4*)(ws_f + WS_PART);
    float*  out     = (float*)d_out;

    hipMemsetAsync(d_ws, 0, (size_t)WS_ZERO_END * 4, stream);  // deg, loss, dD
    k_deg   <<<NE/NT, NT, 0, stream>>>(row, deg);
    k_edge  <<<NE/NT, NT, 0, stream>>>(row, col, types, deg, pos, dD, lossAcc);
    k_steric<<<JSPLIT*NIB, NT, 0, stream>>>(pos, dD, types, partial, lossAcc);
    k_reduce<<<NA/NT, NT, 0, stream>>>(pos, dD, partial, lossAcc, out);
}